// Round 15
// baseline (399.628 us; speedup 1.0000x reference)
//
#include <hip/hip_runtime.h>
#include <hip/hip_bf16.h>

#define BB 8
#define CC 512
#define HO 64
#define HP 66
#define NPIX (BB*HO*HO)   // 32768

typedef float f32x4 __attribute__((ext_vector_type(4)));
typedef __bf16 bf16x8 __attribute__((ext_vector_type(8)));
using bf16 = __hip_bfloat16;

__device__ __forceinline__ void gload16(const void* g, void* l) {
    __builtin_amdgcn_global_load_lds((const __attribute__((address_space(1))) void*)g,
                                     (__attribute__((address_space(3))) void*)l, 16, 0, 0);
}

__device__ __forceinline__ float waveRedSum(float v) {
    #pragma unroll
    for (int off = 32; off; off >>= 1) v += __shfl_down(v, off);
    return v;
}

// ---------------------------------------------------------------------------
// init_all: one launch, three independent jobs branch on blockIdx:
//  [0,2048)     prep_weights conv1/conv2; [2048,3088) halo zero xs1/xs2;
//  [3088,3184)  outrgb init with rgbb[c].
// ---------------------------------------------------------------------------
__global__ void init_all(const float* __restrict__ W1, const float* __restrict__ W2,
                         float* __restrict__ S21, float* __restrict__ S22,
                         bf16* __restrict__ kT1, bf16* __restrict__ kT2, float he,
                         bf16* __restrict__ xs1, bf16* __restrict__ xs2,
                         const float* __restrict__ rgbb, float* __restrict__ outrgb) {
    int blk = blockIdx.x, tid = threadIdx.x;
    if (blk < 2048) {
        int which = blk >> 10;
        const float* Wsrc = which ? W2 : W1;
        float* S2ho = which ? S22 : S21;
        bf16* keffT = which ? kT2 : kT1;
        int t = ((blk & 1023) << 8) + tid;
        int i = t & (CC-1), o = t >> 9;
        const float* wp = Wsrc + (i*CC + o)*9;
        float v[9]; float s2 = 0.f;
        #pragma unroll
        for (int k = 0; k < 9; ++k) { v[k] = wp[k] * he; s2 += v[k]*v[k]; }
        S2ho[o*CC + i] = s2;
        #pragma unroll
        for (int tp = 0; tp < 9; ++tp) keffT[(tp*CC + o)*CC + i] = (bf16)v[8 - tp];
    } else if (blk < 3088) {
        int sub = ((blk - 2048) << 2) + (tid >> 6);   // 0..4159
        int ln = tid & 63;
        bf16* dst = (sub & 1) ? xs2 : xs1;
        int idx = sub >> 1;                 // 0..2079
        int b = idx / 260, rm = idx - b*260;
        int p, q;
        if (rm < 66)       { p = 0;        q = rm; }
        else if (rm < 132) { p = 65;       q = rm - 66; }
        else if (rm < 196) { p = rm - 131; q = 0; }
        else               { p = rm - 195; q = 65; }
        f32x4* d4 = (f32x4*)(dst + ((size_t)((b*HP + p)*HP + q)) * CC);
        d4[ln] = f32x4{0.f, 0.f, 0.f, 0.f};
    } else {
        int t2 = ((blk - 3088) << 2) + (tid >> 6);    // 0..383
        int plane = t2 >> 4;                          // 0..23
        int c = plane - (plane/3)*3;
        float v = rgbb[c];
        *(f32x4*)(outrgb + (plane << 12) + ((t2 & 15) << 8) + ((tid & 63) << 2)) =
            f32x4{v, v, v, v};
    }
}

// one wave per (set, b, i): style[b,i] = sum_d w[b,d]*A[i,d]/sqrt(512) + Ab[i]
__global__ void style_kernel(const float* __restrict__ w,
                             const float* __restrict__ A1, const float* __restrict__ A1b,
                             const float* __restrict__ A2, const float* __restrict__ A2b,
                             float* __restrict__ s1, float* __restrict__ s2) {
    int wid = (blockIdx.x * blockDim.x + threadIdx.x) >> 6;
    int lane = threadIdx.x & 63;
    int set = wid >= BB*CC; int rem = set ? wid - BB*CC : wid;
    int b = rem >> 9, i = rem & (CC-1);
    const float* A = set ? A2 : A1;
    const float* wb = w + b*CC;
    float sum = 0.f;
    for (int d = lane; d < CC; d += 64) sum += wb[d] * A[i*CC + d];
    sum = waveRedSum(sum);
    if (lane == 0) {
        float r = sum * 0.04419417382415922f + (set ? A2b : A1b)[i];
        (set ? s2 : s1)[b*CC + i] = r;
    }
}

// one wave per (set, b, o): dg = gain * rsqrt(sum_i style^2 * S2ho[o][i] + eps)
__global__ void demod_kernel(const float* __restrict__ s1, const float* __restrict__ S21,
                             const float* __restrict__ s2, const float* __restrict__ S22,
                             float* __restrict__ dg1, float* __restrict__ dg2, float gain) {
    int wid = (blockIdx.x * blockDim.x + threadIdx.x) >> 6;
    int lane = threadIdx.x & 63;
    int set = wid >= BB*CC; int rem = set ? wid - BB*CC : wid;
    int b = rem >> 9, o = rem & (CC-1);
    const float* st = (set ? s2 : s1) + b*CC;
    const float* S2 = (set ? S22 : S21) + o*CC;
    float sum = 0.f;
    for (int i = lane; i < CC; i += 64) { float sv = st[i]; sum += sv*sv*S2[i]; }
    sum = waveRedSum(sum);
    if (lane == 0) (set ? dg2 : dg1)[b*CC + o] = gain * rsqrtf(sum + 1e-8f);
}

// block = (b, p): one full output row, 512 threads = channels.
__global__ void upsample_mod(const float* __restrict__ x, const float* __restrict__ s1,
                             bf16* __restrict__ xs1) {
    __shared__ float usl[32][CC];
    int blk = blockIdx.x;                  // b*64 + p
    int i = threadIdx.x;
    int b = blk >> 6, p = blk & 63;
    const float scale = 31.0f / 63.0f;
    float chf = p * scale; int h0 = (int)chf; float fh = chf - h0; int h1 = min(h0 + 1, 31);
    const float* xb = x + ((size_t)(b*CC + i) << 10);
    #pragma unroll
    for (int k = 0; k < 8; ++k) {
        f32x4 r0 = *(const f32x4*)(xb + (h0 << 5) + (k << 2));
        f32x4 r1 = *(const f32x4*)(xb + (h1 << 5) + (k << 2));
        #pragma unroll
        for (int e = 0; e < 4; ++e)
            usl[(k << 2) + e][i] = r0[e]*(1.f - fh) + r1[e]*fh;
    }
    float sv = s1[b*CC + i];
    bf16* op = xs1 + ((size_t)((b*HP + p + 1)*HP + 1))*CC + i;
    #pragma unroll
    for (int q = 0; q < 64; ++q) {
        float cwf = q * scale; int w0 = (int)cwf; float fw = cwf - w0;
        int w1 = min(w0 + 1, 31);
        float v = (usl[w0][i]*(1.f - fw) + usl[w1][i]*fw) * sv;
        op[q*CC] = (bf16)v;
    }
}

// ---------------------------------------------------------------------------
// Implicit-GEMM 3x3 conv. ROUND-15: r14 config (128x128 tile, BK=32, 4 waves,
// 32 KB LDS, 4 blocks/CU — occupancy 40.7% CONFIRMED) with the bank-conflict
// fix. r14's slot^(row&3) swizzle was round-0's conflicted layout (1.887e7):
// at 64B rows, bank = (16*row + 4*slot) mod 32, so lanes l15 and l15+4
// collide. Corrected XOR key = (row>>1)&3: quarter-wave's 16 rows then cover
// each bank exactly TWICE (2-way = free, m136). Same involution on the
// staging SOURCE (rule #21): dest linear, src slot = (tid&3) ^ ((tid>>3)&3).
// Everything else identical to r14. K-order (tap,k0) unchanged.
// ---------------------------------------------------------------------------
#define SB  __builtin_amdgcn_sched_barrier(0)
#define BAR __builtin_amdgcn_s_barrier()
#define VMC(n)  asm volatile("s_waitcnt vmcnt(" #n ")" ::: "memory")
#define HPB (HP*1024)

#define STAGE_A(d, U) do { \
    gload16((U) + aThr,       ldsA + (d)*8192); \
    gload16((U) + aThr + HPB, ldsA + (d)*8192 + 4096); \
} while (0)

#define STAGE_B(d, U) do { \
    gload16((U) + bThr,         ldsB + (d)*8192); \
    gload16((U) + bThr + 65536, ldsB + (d)*8192 + 4096); \
} while (0)

#define LOAD_A(d) do { \
    _Pragma("unroll") \
    for (int fmq = 0; fmq < 4; ++fmq) \
        afr[fmq] = *(const bf16x8*)(aRd + (d)*8192 + fmq*1024 + swz); \
    } while (0)

#define LOAD_B(d) do { \
    _Pragma("unroll") \
    for (int fnq = 0; fnq < 4; ++fnq) \
        bfr[fnq] = *(const bf16x8*)(bRd + (d)*8192 + fnq*1024 + swz); \
    } while (0)

#define MFMA_ALL() do { \
    __builtin_amdgcn_s_setprio(1); \
    _Pragma("unroll") \
    for (int fmq = 0; fmq < 4; ++fmq) \
    { _Pragma("unroll") \
      for (int fnq = 0; fnq < 4; ++fnq) \
        acc[fmq][fnq] = __builtin_amdgcn_mfma_f32_16x16x32_bf16( \
            afr[fmq], bfr[fnq], acc[fmq][fnq], 0, 0, 0); } \
    __builtin_amdgcn_s_setprio(0); } while (0)

// one K-step: stage next step (4 gloads), reads (8 b128), 16 MFMA, one
// vmcnt(0)+barrier (syncs only this block's 4 waves; 3 co-resident blocks
// cover the drain).
#define KSTEP(cur, nxt, aN, bN, doStage) do { \
    if (doStage) { STAGE_A(nxt, aN); STAGE_B(nxt, bN); } \
    LOAD_A(cur); LOAD_B(cur); \
    MFMA_ALL(); \
    VMC(0); SB; BAR; SB; \
} while (0)

// shared preamble + K-loop (expands inside each kernel body)
#define CONV_COMMON \
    __shared__ __attribute__((aligned(16))) bf16 As[8192];  /* 16KB: 2 x 128x32 */ \
    __shared__ __attribute__((aligned(16))) bf16 Bs[8192];  /* 16KB */ \
    const int tid = threadIdx.x; \
    const int wave = tid >> 6, lane = tid & 63; \
    /* XCD swizzle: 1024 wgs, %8==0 -> bijective; 4 ntiles share each A-panel */ \
    const int tileId = ((blockIdx.x & 7) << 7) + (blockIdx.x >> 3); \
    const int mtile = tileId >> 2, ntile = tileId & 3; \
    const int m0 = mtile << 7, n0 = ntile << 7; \
    const int b  = m0 >> 12; \
    const int p0 = (m0 & 4095) >> 6; \
    const int wm = wave >> 1, wn = wave & 1; \
    const int l15 = lane & 15; \
    /* src pre-swizzle: slot fetched = (tid&3) ^ ((row>>1)&3), row = tid>>2 */ \
    const int preswz = (((tid & 3) ^ ((tid >> 3) & 3)) << 4); \
    const int aThr = ((tid >> 2) << 10) + preswz; \
    const int bThr = ((tid >> 2) << 10) + preswz; \
    char* const ldsA = (char*)As + tid*16; \
    char* const ldsB = (char*)Bs + tid*16; \
    const char* const aRd = (const char*)As + (((wm << 6) + l15) << 6); \
    const char* const bRd = (const char*)Bs + (((wn << 6) + l15) << 6); \
    /* read slot' = q ^ ((row>>1)&3), row bits from l15 only */ \
    const int swz = (((lane >> 4) ^ ((l15 >> 1) & 3)) << 4); \
    f32x4 acc[4][4]; \
    _Pragma("unroll") \
    for (int i_ = 0; i_ < 4; ++i_) \
        _Pragma("unroll") \
        for (int j_ = 0; j_ < 4; ++j_) acc[i_][j_] = f32x4{0.f, 0.f, 0.f, 0.f}; \
    bf16x8 afr[4], bfr[4]; \
    auto abase = [&](int st) -> const char* { \
        int t = st >> 4; int dh = (t*11) >> 5; int dw = t - dh*3; \
        return (const char*)xs + ((size_t)((b*HP + p0 + dh)*HP + dw) << 10) + ((st & 15) << 6); \
    }; \
    auto bbase = [&](int st) -> const char* { \
        int t = st >> 4; \
        return (const char*)keffT + ((size_t)(t*CC + n0) << 10) + ((st & 15) << 6); \
    }; \
    { \
        const char* a0 = abase(0); const char* b0 = bbase(0); \
        STAGE_A(0, a0); STAGE_B(0, b0); \
        VMC(0); SB; BAR; SB; \
    } \
    _Pragma("unroll 1") \
    for (int it = 0; it < 72; ++it) { \
        const bool more = (it < 71); \
        const char* aE = abase(2*it + 1); const char* bE = bbase(2*it + 1); \
        const char* aO = abase(2*it + 2); const char* bO = bbase(2*it + 2); \
        KSTEP(0, 1, aE, bE, true); \
        KSTEP(1, 0, aO, bO, more); \
    }

// conv1: writes bf16 padded-NHWC xs2 (pre-multiplied by next style).
__global__ __launch_bounds__(256, 4) void conv_gemm1(
    const bf16* __restrict__ xs, const bf16* __restrict__ keffT,
    const float* __restrict__ dg, const float* __restrict__ noise,
    const float* __restrict__ nsw, const float* __restrict__ nsb,
    const float* __restrict__ nbw, const float* __restrict__ nbb,
    const float* __restrict__ biasv, const float* __restrict__ stnext,
    bf16* __restrict__ outb) {
    CONV_COMMON
    // epilogue: px = m0+wm*64+fm*16+(lane>>4)*4+r; ch = n0+wn*64+fn*16+l15
    const float* dgb = dg + b*CC;
    int nIdx[4]; float pdg[4], pnsw[4], pnsb[4], pnbw[4], pnbb[4], pbias[4], pst[4];
    #pragma unroll
    for (int fn = 0; fn < 4; ++fn) {
        int n = n0 + (wn << 6) + (fn << 4) + l15;
        nIdx[fn] = n;
        pdg[fn] = dgb[n]; pnsw[fn] = nsw[n]; pnsb[fn] = nsb[n];
        pnbw[fn] = nbw[n]; pnbb[fn] = nbb[n]; pbias[fn] = biasv[n];
        pst[fn] = stnext[b*CC + n];
    }
    #pragma unroll
    for (int fm = 0; fm < 4; ++fm) {
        const int mbase = m0 + (wm << 6) + (fm << 4) + ((lane >> 4) << 2);
        const f32x4 nsv = *(const f32x4*)(noise + mbase);
        #pragma unroll
        for (int r = 0; r < 4; ++r) {
            int mloc = mbase + r;
            float ns = nsv[r];
            int prow = (mloc & 4095) >> 6, qcol = mloc & 63;
            #pragma unroll
            for (int fn = 0; fn < 4; ++fn) {
                float v = acc[fm][fn][r] * pdg[fn];
                v = v * (ns*pnsw[fn] + pnsb[fn]) + (ns*pnbw[fn] + pnbb[fn]) + pbias[fn];
                v = fmaxf(v, 0.2f*v);   // leaky relu 0.2
                outb[(((b*HP) + prow + 1)*HP + (qcol + 1))*CC + nIdx[fn]] =
                    (bf16)(v * pst[fn]);
            }
        }
    }
}

// conv2: writes f32 NCHW outx + fused rgb (atomics spread over lanes 0..2).
__global__ __launch_bounds__(256, 4) void conv_gemm2(
    const bf16* __restrict__ xs, const bf16* __restrict__ keffT,
    const float* __restrict__ dg, const float* __restrict__ noise,
    const float* __restrict__ nsw, const float* __restrict__ nsb,
    const float* __restrict__ nbw, const float* __restrict__ nbb,
    const float* __restrict__ biasv, float* __restrict__ outf,
    const float* __restrict__ rgbwv, float* __restrict__ outrgb) {
    CONV_COMMON
    const float* dgb = dg + b*CC;
    int nIdx[4]; float pdg[4], pnsw[4], pnsb[4], pnbw[4], pnbb[4], pbias[4];
    float w0[4], w1[4], w2[4];
    const float heR = 0.03f * 0.04419417382415922f;
    #pragma unroll
    for (int fn = 0; fn < 4; ++fn) {
        int n = n0 + (wn << 6) + (fn << 4) + l15;
        nIdx[fn] = n;
        pdg[fn] = dgb[n]; pnsw[fn] = nsw[n]; pnsb[fn] = nsb[n];
        pnbw[fn] = nbw[n]; pnbb[fn] = nbb[n]; pbias[fn] = biasv[n];
        w0[fn] = rgbwv[n] * heR;
        w1[fn] = rgbwv[CC + n] * heR;
        w2[fn] = rgbwv[2*CC + n] * heR;
    }
    #pragma unroll
    for (int fm = 0; fm < 4; ++fm) {
        const int mbase = m0 + (wm << 6) + (fm << 4) + ((lane >> 4) << 2);
        const f32x4 nsv = *(const f32x4*)(noise + mbase);
        f32x4 pc0 = {0.f,0.f,0.f,0.f}, pc1 = {0.f,0.f,0.f,0.f}, pc2 = {0.f,0.f,0.f,0.f};
        #pragma unroll
        for (int fn = 0; fn < 4; ++fn) {
            f32x4 vv;
            #pragma unroll
            for (int r = 0; r < 4; ++r) {
                float ns = nsv[r];
                float v = acc[fm][fn][r] * pdg[fn];
                v = v * (ns*pnsw[fn] + pnsb[fn]) + (ns*pnbw[fn] + pnbb[fn]) + pbias[fn];
                vv[r] = fmaxf(v, 0.2f*v);
            }
            pc0 += vv * w0[fn]; pc1 += vv * w1[fn]; pc2 += vv * w2[fn];
            *(f32x4*)(outf + ((size_t)(b*CC + nIdx[fn]) << 12) + (mbase & 4095)) = vv;
        }
        // rgb partial: butterfly over the 16 l15 lanes -> all lanes hold sums;
        // lanes 0..2 each issue one atomic.
        #pragma unroll
        for (int r = 0; r < 4; ++r) {
            float a0 = pc0[r], a1 = pc1[r], a2 = pc2[r];
            #pragma unroll
            for (int mk = 1; mk < 16; mk <<= 1) {
                a0 += __shfl_xor(a0, mk);
                a1 += __shfl_xor(a1, mk);
                a2 += __shfl_xor(a2, mk);
            }
            if (l15 < 3) {
                float av = (l15 == 0) ? a0 : (l15 == 1) ? a1 : a2;
                int px = (mbase + r) & 4095;
                atomicAdd(outrgb + (b*3 + l15)*4096 + px, av);
            }
        }
    }
}

extern "C" void kernel_launch(void* const* d_in, const int* in_sizes, int n_in,
                              void* d_out, int out_size, void* d_ws, size_t ws_size,
                              hipStream_t stream) {
    const float* x      = (const float*)d_in[0];
    const float* w      = (const float*)d_in[1];
    const float* noise1 = (const float*)d_in[2];
    const float* noise2 = (const float*)d_in[3];
    const float* conv1w = (const float*)d_in[4];
    const float* bias1  = (const float*)d_in[5];
    const float* conv2w = (const float*)d_in[6];
    const float* bias2  = (const float*)d_in[7];
    const float* A1w = (const float*)d_in[8];
    const float* A1b = (const float*)d_in[9];
    const float* A2w = (const float*)d_in[10];
    const float* A2b = (const float*)d_in[11];
    const float* B1sw = (const float*)d_in[12];
    const float* B1sb = (const float*)d_in[13];
    const float* B1bw = (const float*)d_in[14];
    const float* B1bb = (const float*)d_in[15];
    const float* B2sw = (const float*)d_in[16];
    const float* B2sb = (const float*)d_in[17];
    const float* B2bw = (const float*)d_in[18];
    const float* B2bb = (const float*)d_in[19];
    const float* rgbw = (const float*)d_in[20];
    const float* rgbb = (const float*)d_in[21];

    char* ws = (char*)d_ws;
    size_t off = 0;
    auto alloc = [&](size_t bytes) { char* p = ws + off; off += (bytes + 255) & ~(size_t)255; return p; };
    const size_t xsBytes = (size_t)BB*HP*HP*CC*2;
    bf16* xs1 = (bf16*)alloc(xsBytes);
    bf16* xs2 = (bf16*)alloc(xsBytes);
    bf16* kT1 = (bf16*)alloc((size_t)9*CC*CC*2);
    bf16* kT2 = (bf16*)alloc((size_t)9*CC*CC*2);
    float* S21 = (float*)alloc((size_t)CC*CC*4);
    float* S22 = (float*)alloc((size_t)CC*CC*4);
    float* s1  = (float*)alloc(BB*CC*4);
    float* s2  = (float*)alloc(BB*CC*4);
    float* dg1 = (float*)alloc(BB*CC*4);
    float* dg2 = (float*)alloc(BB*CC*4);

    float* outx   = (float*)d_out;
    float* outrgb = outx + (size_t)BB*CC*HO*HO;

    const float gain = 1.41421356237309515f;
    const float he = gain / sqrtf(512.f * 9.f);
    init_all<<<3184, 256, 0, stream>>>(conv1w, conv2w, S21, S22, kT1, kT2, he,
                                       xs1, xs2, rgbb, outrgb);
    style_kernel<<<2*BB*CC/4, 256, 0, stream>>>(w, A1w, A1b, A2w, A2b, s1, s2);
    demod_kernel<<<2*BB*CC/4, 256, 0, stream>>>(s1, S21, s2, S22, dg1, dg2, gain);
    upsample_mod<<<BB*HO, CC, 0, stream>>>(x, s1, xs1);
    conv_gemm1<<<(NPIX/128)*(CC/128), 256, 0, stream>>>(
        xs1, kT1, dg1, noise1, B1sw, B1sb, B1bw, B1bb, bias1, s2, xs2);
    conv_gemm2<<<(NPIX/128)*(CC/128), 256, 0, stream>>>(
        xs2, kT2, dg2, noise2, B2sw, B2sb, B2bw, B2bb, bias2, outx, rgbw, outrgb);
}

// Round 16
// 318.150 us; speedup vs baseline: 1.2561x; 1.2561x over previous
//
#include <hip/hip_runtime.h>
#include <hip/hip_bf16.h>

#define BB 8
#define CC 512
#define HO 64
#define HP 66
#define NPIX (BB*HO*HO)   // 32768

typedef float f32x4 __attribute__((ext_vector_type(4)));
typedef __bf16 bf16x8 __attribute__((ext_vector_type(8)));
using bf16 = __hip_bfloat16;

__device__ __forceinline__ void gload16(const void* g, void* l) {
    __builtin_amdgcn_global_load_lds((const __attribute__((address_space(1))) void*)g,
                                     (__attribute__((address_space(3))) void*)l, 16, 0, 0);
}

__device__ __forceinline__ float waveRedSum(float v) {
    #pragma unroll
    for (int off = 32; off; off >>= 1) v += __shfl_down(v, off);
    return v;
}

// ---------------------------------------------------------------------------
// init_all: one launch, three independent jobs branch on blockIdx:
//  [0,2048)     prep_weights conv1/conv2; [2048,3088) halo zero xs1/xs2;
//  [3088,3184)  outrgb init with rgbb[c].
// ---------------------------------------------------------------------------
__global__ void init_all(const float* __restrict__ W1, const float* __restrict__ W2,
                         float* __restrict__ S21, float* __restrict__ S22,
                         bf16* __restrict__ kT1, bf16* __restrict__ kT2, float he,
                         bf16* __restrict__ xs1, bf16* __restrict__ xs2,
                         const float* __restrict__ rgbb, float* __restrict__ outrgb) {
    int blk = blockIdx.x, tid = threadIdx.x;
    if (blk < 2048) {
        int which = blk >> 10;
        const float* Wsrc = which ? W2 : W1;
        float* S2ho = which ? S22 : S21;
        bf16* keffT = which ? kT2 : kT1;
        int t = ((blk & 1023) << 8) + tid;
        int i = t & (CC-1), o = t >> 9;
        const float* wp = Wsrc + (i*CC + o)*9;
        float v[9]; float s2 = 0.f;
        #pragma unroll
        for (int k = 0; k < 9; ++k) { v[k] = wp[k] * he; s2 += v[k]*v[k]; }
        S2ho[o*CC + i] = s2;
        #pragma unroll
        for (int tp = 0; tp < 9; ++tp) keffT[(tp*CC + o)*CC + i] = (bf16)v[8 - tp];
    } else if (blk < 3088) {
        int sub = ((blk - 2048) << 2) + (tid >> 6);   // 0..4159
        int ln = tid & 63;
        bf16* dst = (sub & 1) ? xs2 : xs1;
        int idx = sub >> 1;                 // 0..2079
        int b = idx / 260, rm = idx - b*260;
        int p, q;
        if (rm < 66)       { p = 0;        q = rm; }
        else if (rm < 132) { p = 65;       q = rm - 66; }
        else if (rm < 196) { p = rm - 131; q = 0; }
        else               { p = rm - 195; q = 65; }
        f32x4* d4 = (f32x4*)(dst + ((size_t)((b*HP + p)*HP + q)) * CC);
        d4[ln] = f32x4{0.f, 0.f, 0.f, 0.f};
    } else {
        int t2 = ((blk - 3088) << 2) + (tid >> 6);    // 0..383
        int plane = t2 >> 4;                          // 0..23
        int c = plane - (plane/3)*3;
        float v = rgbb[c];
        *(f32x4*)(outrgb + (plane << 12) + ((t2 & 15) << 8) + ((tid & 63) << 2)) =
            f32x4{v, v, v, v};
    }
}

// one wave per (set, b, i): style[b,i] = sum_d w[b,d]*A[i,d]/sqrt(512) + Ab[i]
__global__ void style_kernel(const float* __restrict__ w,
                             const float* __restrict__ A1, const float* __restrict__ A1b,
                             const float* __restrict__ A2, const float* __restrict__ A2b,
                             float* __restrict__ s1, float* __restrict__ s2) {
    int wid = (blockIdx.x * blockDim.x + threadIdx.x) >> 6;
    int lane = threadIdx.x & 63;
    int set = wid >= BB*CC; int rem = set ? wid - BB*CC : wid;
    int b = rem >> 9, i = rem & (CC-1);
    const float* A = set ? A2 : A1;
    const float* wb = w + b*CC;
    float sum = 0.f;
    for (int d = lane; d < CC; d += 64) sum += wb[d] * A[i*CC + d];
    sum = waveRedSum(sum);
    if (lane == 0) {
        float r = sum * 0.04419417382415922f + (set ? A2b : A1b)[i];
        (set ? s2 : s1)[b*CC + i] = r;
    }
}

// one wave per (set, b, o): dg = gain * rsqrt(sum_i style^2 * S2ho[o][i] + eps)
__global__ void demod_kernel(const float* __restrict__ s1, const float* __restrict__ S21,
                             const float* __restrict__ s2, const float* __restrict__ S22,
                             float* __restrict__ dg1, float* __restrict__ dg2, float gain) {
    int wid = (blockIdx.x * blockDim.x + threadIdx.x) >> 6;
    int lane = threadIdx.x & 63;
    int set = wid >= BB*CC; int rem = set ? wid - BB*CC : wid;
    int b = rem >> 9, o = rem & (CC-1);
    const float* st = (set ? s2 : s1) + b*CC;
    const float* S2 = (set ? S22 : S21) + o*CC;
    float sum = 0.f;
    for (int i = lane; i < CC; i += 64) { float sv = st[i]; sum += sv*sv*S2[i]; }
    sum = waveRedSum(sum);
    if (lane == 0) (set ? dg2 : dg1)[b*CC + o] = gain * rsqrtf(sum + 1e-8f);
}

// block = (b, p): one full output row, 512 threads = channels.
// H-lerp hoisted into usl[32][CC]; q-loop unrolled -> static ds_read offsets.
__global__ void upsample_mod(const float* __restrict__ x, const float* __restrict__ s1,
                             bf16* __restrict__ xs1) {
    __shared__ float usl[32][CC];
    int blk = blockIdx.x;                  // b*64 + p
    int i = threadIdx.x;
    int b = blk >> 6, p = blk & 63;
    const float scale = 31.0f / 63.0f;
    float chf = p * scale; int h0 = (int)chf; float fh = chf - h0; int h1 = min(h0 + 1, 31);
    const float* xb = x + ((size_t)(b*CC + i) << 10);
    #pragma unroll
    for (int k = 0; k < 8; ++k) {
        f32x4 r0 = *(const f32x4*)(xb + (h0 << 5) + (k << 2));
        f32x4 r1 = *(const f32x4*)(xb + (h1 << 5) + (k << 2));
        #pragma unroll
        for (int e = 0; e < 4; ++e)
            usl[(k << 2) + e][i] = r0[e]*(1.f - fh) + r1[e]*fh;
    }
    float sv = s1[b*CC + i];
    bf16* op = xs1 + ((size_t)((b*HP + p + 1)*HP + 1))*CC + i;
    #pragma unroll
    for (int q = 0; q < 64; ++q) {
        float cwf = q * scale; int w0 = (int)cwf; float fw = cwf - w0;
        int w1 = min(w0 + 1, 31);
        float v = (usl[w0][i]*(1.f - fw) + usl[w1][i]*fw) * sv;
        op[q*CC] = (bf16)v;
    }
}

// ---------------------------------------------------------------------------
// Implicit-GEMM 3x3 conv — REVERT to round-12's measured-best structure.
// BM=BN=256, BK=64, 512 thr = 8 waves (2Mx4N), per-wave 128x64, barrier-free
// K-step body (stage next step, kc-split reads+MFMAs, ONE vmcnt(0)+barrier
// per step). Measured: conv ~154-155us each, MfmaUtil 44%, 0 conflicts.
// Post-r12 experiments falsified the alternatives: 4-wave/2-block (r13,
// 168us — worse read ratio, same 8 waves/CU), 4-block BK=32 with conflicts
// (r14, 213us) and WITHOUT conflicts (r15, 212us — vmcnt(0) of L2-latency
// loads dominates when all co-resident blocks drain at the same rate).
// 128B LDS rows + slot^(row&7) XOR swizzle both sides (0 conflicts).
// ---------------------------------------------------------------------------
#define SB  __builtin_amdgcn_sched_barrier(0)
#define BAR __builtin_amdgcn_s_barrier()
#define VMC(n)  asm volatile("s_waitcnt vmcnt(" #n ")" ::: "memory")

#define STAGE_A(d, h, U) do { \
    gload16((U) + aThr + (h)*(HP*1024),                 ldsA + (d)*32768 + (h)*16384); \
    gload16((U) + aThr + (h)*(HP*1024) + 2*(HP*1024),   ldsA + (d)*32768 + (h)*16384 + 8192); \
} while (0)

#define STAGE_B(d, h, U) do { \
    gload16((U) + bThr + (h)*32768,                     ldsB + (d)*32768 + (h)*16384); \
    gload16((U) + bThr + (h)*32768 + 131072,            ldsB + (d)*32768 + (h)*16384 + 8192); \
} while (0)

#define LOAD_A(d, fh) do { \
    _Pragma("unroll") \
    for (int fmq = 0; fmq < 4; ++fmq) { \
        afr[fmq][0] = *(const bf16x8*)(aRd + (d)*32768 + (fh)*16384 + fmq*2048 + swz0); \
        afr[fmq][1] = *(const bf16x8*)(aRd + (d)*32768 + (fh)*16384 + fmq*2048 + swz1); \
    } } while (0)

#define LOAD_B(d, nh) do { \
    _Pragma("unroll") \
    for (int fnq = 0; fnq < 2; ++fnq) { \
        bfr[nh][fnq][0] = *(const bf16x8*)(bRd + (d)*32768 + (nh)*16384 + fnq*2048 + swz0); \
        bfr[nh][fnq][1] = *(const bf16x8*)(bRd + (d)*32768 + (nh)*16384 + fnq*2048 + swz1); \
    } } while (0)

#define QUAD(fh, nh) do { \
    __builtin_amdgcn_s_setprio(1); \
    _Pragma("unroll") \
    for (int kc = 0; kc < 2; ++kc) \
    { _Pragma("unroll") \
      for (int fmq = 0; fmq < 4; ++fmq) \
      { _Pragma("unroll") \
        for (int fnq = 0; fnq < 2; ++fnq) \
            acc[(fh)*4+fmq][(nh)*2+fnq] = __builtin_amdgcn_mfma_f32_16x16x32_bf16( \
                afr[fmq][kc], bfr[nh][fnq][kc], acc[(fh)*4+fmq][(nh)*2+fnq], 0, 0, 0); } } \
    __builtin_amdgcn_s_setprio(0); } while (0)

// one K-step, barrier-free inside. cur/nxt: dbuf indices (compile-time).
#define KSTEP(cur, nxt, aN, bN, doStage) do { \
    if (doStage) { \
        STAGE_A(nxt, 0, aN); STAGE_A(nxt, 1, aN); \
        STAGE_B(nxt, 0, bN); STAGE_B(nxt, 1, bN); \
    } \
    LOAD_A(cur, 0); LOAD_B(cur, 0); \
    QUAD(0, 0); \
    LOAD_B(cur, 1); \
    QUAD(0, 1); \
    LOAD_A(cur, 1); \
    QUAD(1, 1); \
    QUAD(1, 0); \
    VMC(0); SB; BAR; SB; \
} while (0)

// shared preamble + K-loop (expands inside each kernel body)
#define CONV_COMMON \
    __shared__ __attribute__((aligned(16))) bf16 As[32768]; \
    __shared__ __attribute__((aligned(16))) bf16 Bs[32768]; \
    const int tid = threadIdx.x; \
    const int wave = tid >> 6, lane = tid & 63; \
    const int tileId = ((blockIdx.x & 7) << 5) + (blockIdx.x >> 3); \
    const int mtile = tileId >> 1, ntile = tileId & 1; \
    const int m0 = mtile << 8, n0 = ntile << 8; \
    const int b  = m0 >> 12; \
    const int p0 = (m0 & 4095) >> 6; \
    const int wm = wave >> 2, wn = wave & 3; \
    const int l15 = lane & 15; \
    const int srcSwz = (((tid & 7) ^ ((tid >> 3) & 7)) << 4); \
    const int aThr = ((tid >> 3) << 10) + srcSwz; \
    const int bThr = (((tid >> 8) & 1) << 16) + (((tid >> 3) & 31) << 10) + srcSwz; \
    char* const ldsA = (char*)As + tid*16; \
    char* const ldsB = (char*)Bs + tid*16; \
    const char* const aRd = (const char*)As + (((wm << 6) + l15) << 7); \
    const char* const bRd = (const char*)Bs + (((wn << 5) + l15) << 7); \
    const int swz0 = (((lane >> 4)    ) ^ (lane & 7)) << 4; \
    const int swz1 = (((lane >> 4) | 4) ^ (lane & 7)) << 4; \
    f32x4 acc[8][4]; \
    _Pragma("unroll") \
    for (int i_ = 0; i_ < 8; ++i_) \
        _Pragma("unroll") \
        for (int j_ = 0; j_ < 4; ++j_) acc[i_][j_] = f32x4{0.f, 0.f, 0.f, 0.f}; \
    bf16x8 afr[4][2], bfr[2][2][2]; \
    auto abase = [&](int st) -> const char* { \
        int t = st >> 3; int dh = (t*11) >> 5; int dw = t - dh*3; \
        return (const char*)xs + ((size_t)((b*HP + p0 + dh)*HP + dw) << 10) + ((st & 7) << 7); \
    }; \
    auto bbase = [&](int st) -> const char* { \
        int t = st >> 3; \
        return (const char*)keffT + ((size_t)(t*CC + n0) << 10) + ((st & 7) << 7); \
    }; \
    { \
        const char* a0 = abase(0); const char* b0 = bbase(0); \
        STAGE_A(0, 0, a0); STAGE_A(0, 1, a0); \
        STAGE_B(0, 0, b0); STAGE_B(0, 1, b0); \
        VMC(0); SB; BAR; SB; \
    } \
    _Pragma("unroll 1") \
    for (int it = 0; it < 36; ++it) { \
        const bool more = (it < 35); \
        const char* aE = abase(2*it + 1); const char* bE = bbase(2*it + 1); \
        const char* aO = abase(2*it + 2); const char* bO = bbase(2*it + 2); \
        KSTEP(0, 1, aE, bE, true); \
        KSTEP(1, 0, aO, bO, more); \
    }

// conv1: writes bf16 padded-NHWC xs2 (pre-multiplied by next style).
__global__ __launch_bounds__(512, 2) void conv_gemm1(
    const bf16* __restrict__ xs, const bf16* __restrict__ keffT,
    const float* __restrict__ dg, const float* __restrict__ noise,
    const float* __restrict__ nsw, const float* __restrict__ nsb,
    const float* __restrict__ nbw, const float* __restrict__ nbb,
    const float* __restrict__ biasv, const float* __restrict__ stnext,
    bf16* __restrict__ outb) {
    CONV_COMMON
    // epilogue: px = m0+wm*128+fm*16+(lane>>4)*4+r; ch = n0+wn*64+fn*16+l15
    const float* dgb = dg + b*CC;
    int nIdx[4]; float pdg[4], pnsw[4], pnsb[4], pnbw[4], pnbb[4], pbias[4], pst[4];
    #pragma unroll
    for (int fn = 0; fn < 4; ++fn) {
        int n = n0 + (wn << 6) + (fn << 4) + l15;
        nIdx[fn] = n;
        pdg[fn] = dgb[n]; pnsw[fn] = nsw[n]; pnsb[fn] = nsb[n];
        pnbw[fn] = nbw[n]; pnbb[fn] = nbb[n]; pbias[fn] = biasv[n];
        pst[fn] = stnext[b*CC + n];
    }
    #pragma unroll
    for (int fm = 0; fm < 8; ++fm) {
        const int mbase = m0 + (wm << 7) + (fm << 4) + ((lane >> 4) << 2);
        const f32x4 nsv = *(const f32x4*)(noise + mbase);
        #pragma unroll
        for (int r = 0; r < 4; ++r) {
            int mloc = mbase + r;
            float ns = nsv[r];
            int prow = (mloc & 4095) >> 6, qcol = mloc & 63;
            #pragma unroll
            for (int fn = 0; fn < 4; ++fn) {
                float v = acc[fm][fn][r] * pdg[fn];
                v = v * (ns*pnsw[fn] + pnsb[fn]) + (ns*pnbw[fn] + pnbb[fn]) + pbias[fn];
                v = fmaxf(v, 0.2f*v);   // leaky relu 0.2
                outb[(((b*HP) + prow + 1)*HP + (qcol + 1))*CC + nIdx[fn]] =
                    (bf16)(v * pst[fn]);
            }
        }
    }
}

// conv2: writes f32 NCHW outx + fused rgb (atomics spread over lanes 0..2).
__global__ __launch_bounds__(512, 2) void conv_gemm2(
    const bf16* __restrict__ xs, const bf16* __restrict__ keffT,
    const float* __restrict__ dg, const float* __restrict__ noise,
    const float* __restrict__ nsw, const float* __restrict__ nsb,
    const float* __restrict__ nbw, const float* __restrict__ nbb,
    const float* __restrict__ biasv, float* __restrict__ outf,
    const float* __restrict__ rgbwv, float* __restrict__ outrgb) {
    CONV_COMMON
    const float* dgb = dg + b*CC;
    int nIdx[4]; float pdg[4], pnsw[4], pnsb[4], pnbw[4], pnbb[4], pbias[4];
    float w0[4], w1[4], w2[4];
    const float heR = 0.03f * 0.04419417382415922f;
    #pragma unroll
    for (int fn = 0; fn < 4; ++fn) {
        int n = n0 + (wn << 6) + (fn << 4) + l15;
        nIdx[fn] = n;
        pdg[fn] = dgb[n]; pnsw[fn] = nsw[n]; pnsb[fn] = nsb[n];
        pnbw[fn] = nbw[n]; pnbb[fn] = nbb[n]; pbias[fn] = biasv[n];
        w0[fn] = rgbwv[n] * heR;
        w1[fn] = rgbwv[CC + n] * heR;
        w2[fn] = rgbwv[2*CC + n] * heR;
    }
    #pragma unroll
    for (int fm = 0; fm < 8; ++fm) {
        const int mbase = m0 + (wm << 7) + (fm << 4) + ((lane >> 4) << 2);
        const f32x4 nsv = *(const f32x4*)(noise + mbase);
        f32x4 pc0 = {0.f,0.f,0.f,0.f}, pc1 = {0.f,0.f,0.f,0.f}, pc2 = {0.f,0.f,0.f,0.f};
        #pragma unroll
        for (int fn = 0; fn < 4; ++fn) {
            f32x4 vv;
            #pragma unroll
            for (int r = 0; r < 4; ++r) {
                float ns = nsv[r];
                float v = acc[fm][fn][r] * pdg[fn];
                v = v * (ns*pnsw[fn] + pnsb[fn]) + (ns*pnbw[fn] + pnbb[fn]) + pbias[fn];
                vv[r] = fmaxf(v, 0.2f*v);
            }
            pc0 += vv * w0[fn]; pc1 += vv * w1[fn]; pc2 += vv * w2[fn];
            *(f32x4*)(outf + ((size_t)(b*CC + nIdx[fn]) << 12) + (mbase & 4095)) = vv;
        }
        // rgb partial: butterfly over the 16 l15 lanes -> all lanes hold sums;
        // lanes 0..2 each issue one atomic.
        #pragma unroll
        for (int r = 0; r < 4; ++r) {
            float a0 = pc0[r], a1 = pc1[r], a2 = pc2[r];
            #pragma unroll
            for (int mk = 1; mk < 16; mk <<= 1) {
                a0 += __shfl_xor(a0, mk);
                a1 += __shfl_xor(a1, mk);
                a2 += __shfl_xor(a2, mk);
            }
            if (l15 < 3) {
                float av = (l15 == 0) ? a0 : (l15 == 1) ? a1 : a2;
                int px = (mbase + r) & 4095;
                atomicAdd(outrgb + (b*3 + l15)*4096 + px, av);
            }
        }
    }
}

extern "C" void kernel_launch(void* const* d_in, const int* in_sizes, int n_in,
                              void* d_out, int out_size, void* d_ws, size_t ws_size,
                              hipStream_t stream) {
    const float* x      = (const float*)d_in[0];
    const float* w      = (const float*)d_in[1];
    const float* noise1 = (const float*)d_in[2];
    const float* noise2 = (const float*)d_in[3];
    const float* conv1w = (const float*)d_in[4];
    const float* bias1  = (const float*)d_in[5];
    const float* conv2w = (const float*)d_in[6];
    const float* bias2  = (const float*)d_in[7];
    const float* A1w = (const float*)d_in[8];
    const float* A1b = (const float*)d_in[9];
    const float* A2w = (const float*)d_in[10];
    const float* A2b = (const float*)d_in[11];
    const float* B1sw = (const float*)d_in[12];
    const float* B1sb = (const float*)d_in[13];
    const float* B1bw = (const float*)d_in[14];
    const float* B1bb = (const float*)d_in[15];
    const float* B2sw = (const float*)d_in[16];
    const float* B2sb = (const float*)d_in[17];
    const float* B2bw = (const float*)d_in[18];
    const float* B2bb = (const float*)d_in[19];
    const float* rgbw = (const float*)d_in[20];
    const float* rgbb = (const float*)d_in[21];

    char* ws = (char*)d_ws;
    size_t off = 0;
    auto alloc = [&](size_t bytes) { char* p = ws + off; off += (bytes + 255) & ~(size_t)255; return p; };
    const size_t xsBytes = (size_t)BB*HP*HP*CC*2;
    bf16* xs1 = (bf16*)alloc(xsBytes);
    bf16* xs2 = (bf16*)alloc(xsBytes);
    bf16* kT1 = (bf16*)alloc((size_t)9*CC*CC*2);
    bf16* kT2 = (bf16*)alloc((size_t)9*CC*CC*2);
    float* S21 = (float*)alloc((size_t)CC*CC*4);
    float* S22 = (float*)alloc((size_t)CC*CC*4);
    float* s1  = (float*)alloc(BB*CC*4);
    float* s2  = (float*)alloc(BB*CC*4);
    float* dg1 = (float*)alloc(BB*CC*4);
    float* dg2 = (float*)alloc(BB*CC*4);

    float* outx   = (float*)d_out;
    float* outrgb = outx + (size_t)BB*CC*HO*HO;

    const float gain = 1.41421356237309515f;
    const float he = gain / sqrtf(512.f * 9.f);
    init_all<<<3184, 256, 0, stream>>>(conv1w, conv2w, S21, S22, kT1, kT2, he,
                                       xs1, xs2, rgbb, outrgb);
    style_kernel<<<2*BB*CC/4, 256, 0, stream>>>(w, A1w, A1b, A2w, A2b, s1, s2);
    demod_kernel<<<2*BB*CC/4, 256, 0, stream>>>(s1, S21, s2, S22, dg1, dg2, gain);
    upsample_mod<<<BB*HO, CC, 0, stream>>>(x, s1, xs1);
    conv_gemm1<<<(NPIX/256)*(CC/256), 512, 0, stream>>>(
        xs1, kT1, dg1, noise1, B1sw, B1sb, B1bw, B1bb, bias1, s2, xs2);
    conv_gemm2<<<(NPIX/256)*(CC/256), 512, 0, stream>>>(
        xs2, kT2, dg2, noise2, B2sw, B2sb, B2bw, B2bb, bias2, outx, rgbw, outrgb);
}